// Round 8
// baseline (475.352 us; speedup 1.0000x reference)
//
#include <hip/hip_runtime.h>
#include <cstdint>
#include <cstddef>

#define M_DIM 8192
#define N_DIM 4096
#define K_DIM 4096

#define BM 128
#define BN 128
#define BK 128   // i8 elements of K per tile

typedef int int32x4 __attribute__((ext_vector_type(4)));

// ws layout:
//   int32 header (64 KB):
//     [0] = flagA (1 -> stored packed int8, 0 -> widened int32)
//     [1] = flagB
//     [16 .. 16+N)      rowsum(W) per output channel (written directly, no atomics)
//   byte 65536:           A8  (M*K int8)
//   byte 65536 + M*K:     W8  (N*K int8)

typedef __attribute__((address_space(1))) const void* gas_cptr;
typedef __attribute__((address_space(3))) void* las_ptr;

__device__ __forceinline__ void async_copy16(const void* g, void* l) {
    __builtin_amdgcn_global_load_lds((gas_cptr)g, (las_ptr)l, 16, 0, 0);
}

__device__ __forceinline__ int32x4 pack16(const int* p) {
    const int32x4* v = (const int32x4*)p;
    int32x4 w0 = v[0], w1 = v[1], w2 = v[2], w3 = v[3];
    int32x4 r;
    r.x = (w0.x & 0xFF) | ((w0.y & 0xFF) << 8) | ((w0.z & 0xFF) << 16) | (w0.w << 24);
    r.y = (w1.x & 0xFF) | ((w1.y & 0xFF) << 8) | ((w1.z & 0xFF) << 16) | (w1.w << 24);
    r.z = (w2.x & 0xFF) | ((w2.y & 0xFF) << 8) | ((w2.z & 0xFF) << 16) | (w2.w << 24);
    r.w = (w3.x & 0xFF) | ((w3.y & 0xFF) << 8) | ((w3.z & 0xFF) << 16) | (w3.w << 24);
    return r;
}

__global__ void ql_detect_kernel(const int* a, const int* b, int* ws) {
    int t = threadIdx.x;  // 64 threads
    int fa = 0, fb = 0;
    for (int i = t; i < 4096; i += 64) {
        int va = a[i]; if (va > 127 || va < -128) fa = 1;
        int vb = b[i]; if (vb > 127 || vb < -128) fb = 1;
    }
    unsigned long long ba = __ballot(fa);
    unsigned long long bb = __ballot(fb);
    if (t == 0) { ws[0] = ba ? 1 : 0; ws[1] = bb ? 1 : 0; }
}

// One launch packs both tensors and computes W rowsums.
// Blocks [0, N/4):        W rows, one wave per row (rowsum written directly).
// Blocks [N/4, N/4+M*K/4096): A chunks, 1024 dwords per block.
__global__ __launch_bounds__(256)
void ql_pack_all_kernel(const void* asrc, const void* bsrc, int* adst, int* bdst,
                        int* ws) {
    const int fa = __builtin_amdgcn_readfirstlane(ws[0]);
    const int fb = __builtin_amdgcn_readfirstlane(ws[1]);
    const int t    = threadIdx.x;
    const int lane = t & 63;
    const int wid  = t >> 6;

    if (blockIdx.x < N_DIM / 4) {
        // ---- W part: row per wave ----
        const int n = blockIdx.x * 4 + wid;
        int s = 0;
        if (fb) {
            const int* src = (const int*)bsrc + (size_t)n * (K_DIM / 4);
#pragma unroll
            for (int it = 0; it < 4; ++it) {
                const int c = it * 64 + lane;
                int w = src[c];
                bdst[(size_t)n * (K_DIM / 4) + c] = w;
                s += (int)(int8_t)(w) + (int)(int8_t)(w >> 8)
                   + (int)(int8_t)(w >> 16) + (w >> 24);
            }
        } else {
            const int32x4* src = (const int32x4*)bsrc + (size_t)n * (K_DIM / 4);
#pragma unroll
            for (int it = 0; it < 16; ++it) {
                const int c = it * 64 + lane;
                int32x4 v = src[c];
                int w = (v.x & 0xFF) | ((v.y & 0xFF) << 8)
                      | ((v.z & 0xFF) << 16) | (v.w << 24);
                bdst[(size_t)n * (K_DIM / 4) + c] = w;
                s += v.x + v.y + v.z + v.w;
            }
        }
#pragma unroll
        for (int off = 32; off > 0; off >>= 1) s += __shfl_down(s, off, 64);
        if (lane == 0) ws[16 + n] = s;
    } else {
        // ---- A part: 1024 output dwords per block ----
        const long base = (long)(blockIdx.x - N_DIM / 4) * 1024;
        if (fa) {
#pragma unroll
            for (int it = 0; it < 4; ++it) {
                const long c = base + it * 256 + t;
                adst[c] = ((const int*)asrc)[c];
            }
        } else {
#pragma unroll
            for (int it = 0; it < 4; ++it) {
                const long c = base + it * 256 + t;
                int32x4 v = ((const int32x4*)asrc)[c];
                adst[c] = (v.x & 0xFF) | ((v.y & 0xFF) << 8)
                        | ((v.z & 0xFF) << 16) | (v.w << 24);
            }
        }
    }
}

__device__ __forceinline__ int acc_elem(const int32x4& a, int r) {
    return (r == 0) ? a.x : (r == 1) ? a.y : (r == 2) ? a.z : a.w;
}

// Epilogue: requantize inline (params computed from qbias/wscale/rowsum).
__device__ __forceinline__ void ql_epilogue(int32x4 acc[4][4], const int* rs,
                                            const int* qbias, const float* wscale,
                                            int* out, int bm, int bn,
                                            int wm, int wn, int qm, int qh) {
#pragma unroll
    for (int j = 0; j < 4; ++j) {
        const int n_g = bn * BN + wn + j * 16 + qm;
        const int b0 = qbias[n_g] + 3 * rs[n_g];             // qbias - rowsum*Zin, Zin=-3
        float folded = (0.05f * wscale[n_g]) / 0.1f;         // in (0,1)
        const int f0 = (int)(7.0f - ceilf(log2f(folded)));
        const int s0 = (int)rintf(folded * exp2f((float)f0)); // nearest-even == np.round
#pragma unroll
        for (int i = 0; i < 4; ++i) {
            const int m_base = bm * BM + wm + i * 16 + qh * 4;
#pragma unroll
            for (int r = 0; r < 4; ++r) {
                int v = acc_elem(acc[i][j], r) + b0;
                long long p = (long long)v * (long long)s0;
                int o = (int)(p >> f0) - 5;            // + OUTPUT_ZERO_POINT (-5)
                o = o < -128 ? -128 : (o > 127 ? 127 : o);
                out[(size_t)(m_base + r) * N_DIM + n_g] = o;
            }
        }
    }
}

// Fast path: verified round-3 K-loop (single-buffer LDS, XOR swizzle,
// global_load_lds).  Grid TRANSPOSED for L2/L3 locality: bm = blockIdx.x
// (fastest) so temporally-close blocks share the same 512 KB W slab and A
// stays L3-resident.
__global__ __launch_bounds__(256)
void ql_gemm_kernel(const int8_t* aptr, const int8_t* bptr, const int* ws,
                    const int* qbias, const float* wscale, int* out) {
    __shared__ int32x4 Als[BM * BK / 16];   // 16 KB
    __shared__ int32x4 Bls[BN * BK / 16];   // 16 KB

    const int t    = threadIdx.x;
    const int lane = t & 63;
    const int wid  = t >> 6;
    const int bm = blockIdx.x;      // M/128 = 64  (fastest-varying)
    const int bn = blockIdx.y;      // N/128 = 32

    const int wm = (wid >> 1) * 64;
    const int wn = (wid & 1) * 64;
    const int qm = lane & 15;
    const int qh = lane >> 4;

    int32x4 acc[4][4] = {};

    for (int kt = 0; kt < K_DIM / BK; ++kt) {
        __syncthreads();
        const int k0 = kt * BK;
#pragma unroll
        for (int r = 0; r < 4; ++r) {
            const int c    = r * 256 + t;                 // LDS chunk id 0..1023
            const int row  = c >> 3;
            const int colg = (c & 7) ^ (row & 7);         // inverse swizzle on source
            const size_t offA = (size_t)(bm * BM + row) * K_DIM + k0 + colg * 16;
            const size_t offB = (size_t)(bn * BN + row) * K_DIM + k0 + colg * 16;
            async_copy16(aptr + offA, &Als[c]);
            async_copy16(bptr + offB, &Bls[c]);
        }
        __syncthreads();

#pragma unroll
        for (int s = 0; s < 2; ++s) {
            const int colk = s * 4 + qh;                  // k-chunk 0..7 within BK
            int32x4 af[4], bf[4];
#pragma unroll
            for (int i = 0; i < 4; ++i) {
                const int ra = wm + i * 16 + qm;
                const int rb = wn + i * 16 + qm;
                af[i] = Als[ra * 8 + (colk ^ (ra & 7))];
                bf[i] = Bls[rb * 8 + (colk ^ (rb & 7))];
            }
#pragma unroll
            for (int i = 0; i < 4; ++i)
#pragma unroll
                for (int j = 0; j < 4; ++j)
                    acc[i][j] = __builtin_amdgcn_mfma_i32_16x16x64_i8(
                        af[i], bf[j], acc[i][j], 0, 0, 0);
        }
    }
    ql_epilogue(acc, ws + 16, qbias, wscale, out, bm, bn, wm, wn, qm, qh);
}

// Fallback rowsum prep (ws too small): writes rowsum only.
__global__ void ql_prep_kernel(const void* wptr, int* ws) {
    const int lane = threadIdx.x & 63;
    const int wid  = threadIdx.x >> 6;
    const int n = blockIdx.x * 4 + wid;
    const int b8 = __builtin_amdgcn_readfirstlane(ws[1]);

    int s = 0;
    if (b8) {
        const int32x4* row = (const int32x4*)((const int8_t*)wptr + (size_t)n * K_DIM);
        for (int c = lane; c < K_DIM / 16; c += 64) {
            int32x4 v = row[c];
#pragma unroll
            for (int j = 0; j < 4; ++j) {
                int w = (j == 0) ? v.x : (j == 1) ? v.y : (j == 2) ? v.z : v.w;
                s += (int)(int8_t)(w) + (int)(int8_t)(w >> 8)
                   + (int)(int8_t)(w >> 16) + (w >> 24);
            }
        }
    } else {
        const int32x4* row = (const int32x4*)((const int*)wptr + (size_t)n * K_DIM);
        for (int c = lane; c < K_DIM / 4; c += 64) {
            int32x4 v = row[c];
            s += v.x + v.y + v.z + v.w;
        }
    }
#pragma unroll
    for (int off = 32; off > 0; off >>= 1) s += __shfl_down(s, off, 64);
    if (lane == 0) ws[16 + n] = s;
}

// Fallback GEMM (ws too small): packs in-loop.
__global__ __launch_bounds__(256)
void ql_gemm_fb_kernel(const void* aptr, const void* bptr, const int* ws,
                       const int* qbias, const float* wscale, int* out) {
    __shared__ int32x4 Als[BM * BK / 16];
    __shared__ int32x4 Bls[BN * BK / 16];

    const int a8 = __builtin_amdgcn_readfirstlane(ws[0]);
    const int b8 = __builtin_amdgcn_readfirstlane(ws[1]);

    const int t    = threadIdx.x;
    const int lane = t & 63;
    const int wid  = t >> 6;
    const int bm = blockIdx.x;
    const int bn = blockIdx.y;

    const int wm = (wid >> 1) * 64;
    const int wn = (wid & 1) * 64;
    const int qm = lane & 15;
    const int qh = lane >> 4;

    int32x4 acc[4][4] = {};

    for (int kt = 0; kt < K_DIM / BK; ++kt) {
        __syncthreads();
        const int k0 = kt * BK;
#pragma unroll
        for (int r = 0; r < 4; ++r) {
            const int c    = r * 256 + t;
            const int row  = c >> 3;
            const int colg = (c & 7) ^ (row & 7);
            const size_t offA = (size_t)(bm * BM + row) * K_DIM + k0 + colg * 16;
            const size_t offB = (size_t)(bn * BN + row) * K_DIM + k0 + colg * 16;
            if (a8) async_copy16((const int8_t*)aptr + offA, &Als[c]);
            else    Als[c] = pack16((const int*)aptr + offA);
            if (b8) async_copy16((const int8_t*)bptr + offB, &Bls[c]);
            else    Bls[c] = pack16((const int*)bptr + offB);
        }
        __syncthreads();

#pragma unroll
        for (int s = 0; s < 2; ++s) {
            const int colk = s * 4 + qh;
            int32x4 af[4], bf[4];
#pragma unroll
            for (int i = 0; i < 4; ++i) {
                const int ra = wm + i * 16 + qm;
                const int rb = wn + i * 16 + qm;
                af[i] = Als[ra * 8 + (colk ^ (ra & 7))];
                bf[i] = Bls[rb * 8 + (colk ^ (rb & 7))];
            }
#pragma unroll
            for (int i = 0; i < 4; ++i)
#pragma unroll
                for (int j = 0; j < 4; ++j)
                    acc[i][j] = __builtin_amdgcn_mfma_i32_16x16x64_i8(
                        af[i], bf[j], acc[i][j], 0, 0, 0);
        }
    }
    ql_epilogue(acc, ws + 16, qbias, wscale, out, bm, bn, wm, wn, qm, qh);
}

extern "C" void kernel_launch(void* const* d_in, const int* in_sizes, int n_in,
                              void* d_out, int out_size, void* d_ws, size_t ws_size,
                              hipStream_t stream) {
    const void* qin    = d_in[0];
    const void* qwt    = d_in[1];
    const int* qbias   = (const int*)d_in[2];
    const float* wscal = (const float*)d_in[3];
    int* ws  = (int*)d_ws;
    int* out = (int*)d_out;

    hipLaunchKernelGGL(ql_detect_kernel, dim3(1), dim3(64), 0, stream,
                       (const int*)qin, (const int*)qwt, ws);

    const size_t need = 65536 + (size_t)M_DIM * K_DIM + (size_t)N_DIM * K_DIM;
    if (ws_size >= need) {
        int8_t* a8 = (int8_t*)d_ws + 65536;
        int8_t* w8 = a8 + (size_t)M_DIM * K_DIM;
        // W rows: N/4 blocks; A chunks: M*K/4096 blocks
        const unsigned packGrid = N_DIM / 4 + (unsigned)((size_t)M_DIM * K_DIM / 4096);
        hipLaunchKernelGGL(ql_pack_all_kernel, dim3(packGrid), dim3(256), 0, stream,
                           qin, qwt, (int*)a8, (int*)w8, ws);
        hipLaunchKernelGGL(ql_gemm_kernel, dim3(M_DIM / BM, N_DIM / BN), dim3(256),
                           0, stream, a8, w8, ws, qbias, wscal, out);
    } else {
        hipLaunchKernelGGL(ql_prep_kernel, dim3(N_DIM / 4), dim3(256), 0, stream,
                           qwt, ws);
        hipLaunchKernelGGL(ql_gemm_fb_kernel, dim3(M_DIM / BM, N_DIM / BN), dim3(256),
                           0, stream, qin, qwt, ws, qbias, wscal, out);
    }
}

// Round 9
// 440.981 us; speedup vs baseline: 1.0779x; 1.0779x over previous
//
#include <hip/hip_runtime.h>
#include <cstdint>
#include <cstddef>

#define M_DIM 8192
#define N_DIM 4096
#define K_DIM 4096

#define BM 128
#define BN 128
#define BK 128   // i8 elements of K per tile

typedef int int32x4  __attribute__((ext_vector_type(4)));
typedef int int32x16 __attribute__((ext_vector_type(16)));

// ws layout:
//   int32 header (64 KB):
//     [0] = flagA (1 -> stored packed int8, 0 -> widened int32)
//     [1] = flagB
//     [16 .. 16+N)      rowsum(W) per output channel
//   byte 65536:           A8  (M*K int8)
//   byte 65536 + M*K:     W8  (N*K int8)

typedef __attribute__((address_space(1))) const void* gas_cptr;
typedef __attribute__((address_space(3))) void* las_ptr;

__device__ __forceinline__ void async_copy16(const void* g, void* l) {
    __builtin_amdgcn_global_load_lds((gas_cptr)g, (las_ptr)l, 16, 0, 0);
}

__device__ __forceinline__ int32x4 pack16(const int* p) {
    const int32x4* v = (const int32x4*)p;
    int32x4 w0 = v[0], w1 = v[1], w2 = v[2], w3 = v[3];
    int32x4 r;
    r.x = (w0.x & 0xFF) | ((w0.y & 0xFF) << 8) | ((w0.z & 0xFF) << 16) | (w0.w << 24);
    r.y = (w1.x & 0xFF) | ((w1.y & 0xFF) << 8) | ((w1.z & 0xFF) << 16) | (w1.w << 24);
    r.z = (w2.x & 0xFF) | ((w2.y & 0xFF) << 8) | ((w2.z & 0xFF) << 16) | (w2.w << 24);
    r.w = (w3.x & 0xFF) | ((w3.y & 0xFF) << 8) | ((w3.z & 0xFF) << 16) | (w3.w << 24);
    return r;
}

__global__ void ql_detect_kernel(const int* a, const int* b, int* ws) {
    int t = threadIdx.x;  // 64 threads
    int fa = 0, fb = 0;
    for (int i = t; i < 4096; i += 64) {
        int va = a[i]; if (va > 127 || va < -128) fa = 1;
        int vb = b[i]; if (vb > 127 || vb < -128) fb = 1;
    }
    unsigned long long ba = __ballot(fa);
    unsigned long long bb = __ballot(fb);
    if (t == 0) { ws[0] = ba ? 1 : 0; ws[1] = bb ? 1 : 0; }
}

// One launch packs both tensors and computes W rowsums.
// Blocks [0, N/4):        W rows, one wave per row (rowsum written directly).
// Blocks [N/4, N/4+M*K/4096): A chunks, 1024 dwords per block.
__global__ __launch_bounds__(256)
void ql_pack_all_kernel(const void* asrc, const void* bsrc, int* adst, int* bdst,
                        int* ws) {
    const int fa = __builtin_amdgcn_readfirstlane(ws[0]);
    const int fb = __builtin_amdgcn_readfirstlane(ws[1]);
    const int t    = threadIdx.x;
    const int lane = t & 63;
    const int wid  = t >> 6;

    if (blockIdx.x < N_DIM / 4) {
        const int n = blockIdx.x * 4 + wid;
        int s = 0;
        if (fb) {
            const int* src = (const int*)bsrc + (size_t)n * (K_DIM / 4);
#pragma unroll
            for (int it = 0; it < 4; ++it) {
                const int c = it * 64 + lane;
                int w = src[c];
                bdst[(size_t)n * (K_DIM / 4) + c] = w;
                s += (int)(int8_t)(w) + (int)(int8_t)(w >> 8)
                   + (int)(int8_t)(w >> 16) + (w >> 24);
            }
        } else {
            const int32x4* src = (const int32x4*)bsrc + (size_t)n * (K_DIM / 4);
#pragma unroll
            for (int it = 0; it < 16; ++it) {
                const int c = it * 64 + lane;
                int32x4 v = src[c];
                int w = (v.x & 0xFF) | ((v.y & 0xFF) << 8)
                      | ((v.z & 0xFF) << 16) | (v.w << 24);
                bdst[(size_t)n * (K_DIM / 4) + c] = w;
                s += v.x + v.y + v.z + v.w;
            }
        }
#pragma unroll
        for (int off = 32; off > 0; off >>= 1) s += __shfl_down(s, off, 64);
        if (lane == 0) ws[16 + n] = s;
    } else {
        const long base = (long)(blockIdx.x - N_DIM / 4) * 1024;
        if (fa) {
#pragma unroll
            for (int it = 0; it < 4; ++it) {
                const long c = base + it * 256 + t;
                adst[c] = ((const int*)asrc)[c];
            }
        } else {
#pragma unroll
            for (int it = 0; it < 4; ++it) {
                const long c = base + it * 256 + t;
                int32x4 v = ((const int32x4*)asrc)[c];
                adst[c] = (v.x & 0xFF) | ((v.y & 0xFF) << 8)
                        | ((v.z & 0xFF) << 16) | (v.w << 24);
            }
        }
    }
}

__device__ __forceinline__ int acc_elem4(const int32x4& a, int r) {
    return (r == 0) ? a.x : (r == 1) ? a.y : (r == 2) ? a.z : a.w;
}

// Fast path: round-7 grid order (bn = blockIdx.x), verified staging structure,
// 32x32x32 i8 MFMA (4404 TOPS rate, half the MFMA issue slots).
__global__ __launch_bounds__(256)
void ql_gemm_kernel(const int8_t* aptr, const int8_t* bptr, const int* ws,
                    const int* qbias, const float* wscale, int* out) {
    __shared__ int32x4 Als[BM * BK / 16];   // 16 KB
    __shared__ int32x4 Bls[BN * BK / 16];   // 16 KB

    const int t    = threadIdx.x;
    const int lane = t & 63;
    const int wid  = t >> 6;
    const int bn = blockIdx.x;      // N/128 = 32  (fastest, round-7 order)
    const int bm = blockIdx.y;      // M/128 = 64

    const int wm = (wid >> 1) * 64;
    const int wn = (wid & 1) * 64;
    const int l31 = lane & 31;      // row within 32-row fragment
    const int lh  = lane >> 5;      // 0/1: k-half within K=32
    const int l7  = lane & 7;       // swizzle key (wm/wn/i*32 are all ≡0 mod 8)

    int32x16 acc[2][2] = {};

    for (int kt = 0; kt < K_DIM / BK; ++kt) {
        __syncthreads();
        const int k0 = kt * BK;
#pragma unroll
        for (int r = 0; r < 4; ++r) {
            const int c    = r * 256 + t;                 // LDS chunk id 0..1023
            const int row  = c >> 3;
            const int colg = (c & 7) ^ (row & 7);         // inverse swizzle on source
            const size_t offA = (size_t)(bm * BM + row) * K_DIM + k0 + colg * 16;
            const size_t offB = (size_t)(bn * BN + row) * K_DIM + k0 + colg * 16;
            async_copy16(aptr + offA, &Als[c]);
            async_copy16(bptr + offB, &Bls[c]);
        }
        __syncthreads();

#pragma unroll
        for (int ks = 0; ks < 4; ++ks) {                  // K=32 steps within BK
            const int colk = ks * 2 + lh;                 // k-chunk 0..7
            int32x4 af[2], bf[2];
#pragma unroll
            for (int i = 0; i < 2; ++i) {
                const int ra = wm + i * 32 + l31;
                const int rb = wn + i * 32 + l31;
                af[i] = Als[ra * 8 + (colk ^ l7)];
                bf[i] = Bls[rb * 8 + (colk ^ l7)];
            }
#pragma unroll
            for (int i = 0; i < 2; ++i)
#pragma unroll
                for (int j = 0; j < 2; ++j)
                    acc[i][j] = __builtin_amdgcn_mfma_i32_32x32x32_i8(
                        af[i], bf[j], acc[i][j], 0, 0, 0);
        }
    }

    // epilogue: requantize inline; C/D layout col=lane&31,
    // row=(reg&3)+8*(reg>>2)+4*(lane>>5)
    const int* rs = ws + 16;
#pragma unroll
    for (int j = 0; j < 2; ++j) {
        const int n_g = bn * BN + wn + j * 32 + l31;
        const int b0 = qbias[n_g] + 3 * rs[n_g];             // qbias - rowsum*Zin
        float folded = (0.05f * wscale[n_g]) / 0.1f;         // in (0,1)
        const int f0 = (int)(7.0f - ceilf(log2f(folded)));
        const int s0 = (int)rintf(folded * exp2f((float)f0));
#pragma unroll
        for (int i = 0; i < 2; ++i) {
            const int m_base = bm * BM + wm + i * 32 + lh * 4;
#pragma unroll
            for (int r = 0; r < 16; ++r) {
                const int row = m_base + (r & 3) + 8 * (r >> 2);
                int v = acc[i][j][r] + b0;
                long long p = (long long)v * (long long)s0;
                int o = (int)(p >> f0) - 5;            // + OUTPUT_ZERO_POINT (-5)
                o = o < -128 ? -128 : (o > 127 ? 127 : o);
                out[(size_t)row * N_DIM + n_g] = o;
            }
        }
    }
}

// Fallback rowsum prep (ws too small).
__global__ void ql_prep_kernel(const void* wptr, int* ws) {
    const int lane = threadIdx.x & 63;
    const int wid  = threadIdx.x >> 6;
    const int n = blockIdx.x * 4 + wid;
    const int b8 = __builtin_amdgcn_readfirstlane(ws[1]);

    int s = 0;
    if (b8) {
        const int32x4* row = (const int32x4*)((const int8_t*)wptr + (size_t)n * K_DIM);
        for (int c = lane; c < K_DIM / 16; c += 64) {
            int32x4 v = row[c];
#pragma unroll
            for (int j = 0; j < 4; ++j) {
                int w = (j == 0) ? v.x : (j == 1) ? v.y : (j == 2) ? v.z : v.w;
                s += (int)(int8_t)(w) + (int)(int8_t)(w >> 8)
                   + (int)(int8_t)(w >> 16) + (w >> 24);
            }
        }
    } else {
        const int32x4* row = (const int32x4*)((const int*)wptr + (size_t)n * K_DIM);
        for (int c = lane; c < K_DIM / 4; c += 64) {
            int32x4 v = row[c];
            s += v.x + v.y + v.z + v.w;
        }
    }
#pragma unroll
    for (int off = 32; off > 0; off >>= 1) s += __shfl_down(s, off, 64);
    if (lane == 0) ws[16 + n] = s;
}

// Fallback GEMM (ws too small): round-3 16x16 structure, packs in-loop.
__global__ __launch_bounds__(256)
void ql_gemm_fb_kernel(const void* aptr, const void* bptr, const int* ws,
                       const int* qbias, const float* wscale, int* out) {
    __shared__ int32x4 Als[BM * BK / 16];
    __shared__ int32x4 Bls[BN * BK / 16];

    const int a8 = __builtin_amdgcn_readfirstlane(ws[0]);
    const int b8 = __builtin_amdgcn_readfirstlane(ws[1]);

    const int t    = threadIdx.x;
    const int lane = t & 63;
    const int wid  = t >> 6;
    const int bn = blockIdx.x;
    const int bm = blockIdx.y;

    const int wm = (wid >> 1) * 64;
    const int wn = (wid & 1) * 64;
    const int qm = lane & 15;
    const int qh = lane >> 4;

    int32x4 acc[4][4] = {};

    for (int kt = 0; kt < K_DIM / BK; ++kt) {
        __syncthreads();
        const int k0 = kt * BK;
#pragma unroll
        for (int r = 0; r < 4; ++r) {
            const int c    = r * 256 + t;
            const int row  = c >> 3;
            const int colg = (c & 7) ^ (row & 7);
            const size_t offA = (size_t)(bm * BM + row) * K_DIM + k0 + colg * 16;
            const size_t offB = (size_t)(bn * BN + row) * K_DIM + k0 + colg * 16;
            if (a8) async_copy16((const int8_t*)aptr + offA, &Als[c]);
            else    Als[c] = pack16((const int*)aptr + offA);
            if (b8) async_copy16((const int8_t*)bptr + offB, &Bls[c]);
            else    Bls[c] = pack16((const int*)bptr + offB);
        }
        __syncthreads();

#pragma unroll
        for (int s = 0; s < 2; ++s) {
            const int colk = s * 4 + qh;
            int32x4 af[4], bf[4];
#pragma unroll
            for (int i = 0; i < 4; ++i) {
                const int ra = wm + i * 16 + qm;
                const int rb = wn + i * 16 + qm;
                af[i] = Als[ra * 8 + (colk ^ (ra & 7))];
                bf[i] = Bls[rb * 8 + (colk ^ (rb & 7))];
            }
#pragma unroll
            for (int i = 0; i < 4; ++i)
#pragma unroll
                for (int j = 0; j < 4; ++j)
                    acc[i][j] = __builtin_amdgcn_mfma_i32_16x16x64_i8(
                        af[i], bf[j], acc[i][j], 0, 0, 0);
        }
    }

    const int* rs = ws + 16;
#pragma unroll
    for (int j = 0; j < 4; ++j) {
        const int n_g = bn * BN + wn + j * 16 + qm;
        const int b0 = qbias[n_g] + 3 * rs[n_g];
        float folded = (0.05f * wscale[n_g]) / 0.1f;
        const int f0 = (int)(7.0f - ceilf(log2f(folded)));
        const int s0 = (int)rintf(folded * exp2f((float)f0));
#pragma unroll
        for (int i = 0; i < 4; ++i) {
            const int m_base = bm * BM + wm + i * 16 + qh * 4;
#pragma unroll
            for (int r = 0; r < 4; ++r) {
                int v = acc_elem4(acc[i][j], r) + b0;
                long long p = (long long)v * (long long)s0;
                int o = (int)(p >> f0) - 5;
                o = o < -128 ? -128 : (o > 127 ? 127 : o);
                out[(size_t)(m_base + r) * N_DIM + n_g] = o;
            }
        }
    }
}

extern "C" void kernel_launch(void* const* d_in, const int* in_sizes, int n_in,
                              void* d_out, int out_size, void* d_ws, size_t ws_size,
                              hipStream_t stream) {
    const void* qin    = d_in[0];
    const void* qwt    = d_in[1];
    const int* qbias   = (const int*)d_in[2];
    const float* wscal = (const float*)d_in[3];
    int* ws  = (int*)d_ws;
    int* out = (int*)d_out;

    hipLaunchKernelGGL(ql_detect_kernel, dim3(1), dim3(64), 0, stream,
                       (const int*)qin, (const int*)qwt, ws);

    const size_t need = 65536 + (size_t)M_DIM * K_DIM + (size_t)N_DIM * K_DIM;
    if (ws_size >= need) {
        int8_t* a8 = (int8_t*)d_ws + 65536;
        int8_t* w8 = a8 + (size_t)M_DIM * K_DIM;
        const unsigned packGrid = N_DIM / 4 + (unsigned)((size_t)M_DIM * K_DIM / 4096);
        hipLaunchKernelGGL(ql_pack_all_kernel, dim3(packGrid), dim3(256), 0, stream,
                           qin, qwt, (int*)a8, (int*)w8, ws);
        hipLaunchKernelGGL(ql_gemm_kernel, dim3(N_DIM / BN, M_DIM / BM), dim3(256),
                           0, stream, a8, w8, ws, qbias, wscal, out);
    } else {
        hipLaunchKernelGGL(ql_prep_kernel, dim3(N_DIM / 4), dim3(256), 0, stream,
                           qwt, ws);
        hipLaunchKernelGGL(ql_gemm_fb_kernel, dim3(N_DIM / BN, M_DIM / BM), dim3(256),
                           0, stream, qin, qwt, ws, qbias, wscal, out);
    }
}